// Round 1
// baseline (577.446 us; speedup 1.0000x reference)
//
#include <hip/hip_runtime.h>

// Shift-TCN fused pipeline, MI355X (gfx950).
// Stages: [K0] w fp32->bf16  [K1] BN1 stats  [K2] BN1-affine + shift_in -> h_t (bf16, K-contig)
//         [K3] MFMA bf16 GEMM + bias + relu -> y (bf16)  [K4] shift_out + BN2 stats
//         [K5] shift_out + BN2 affine -> out (fp32)

#define EPSV 1e-5f
constexpr int Nn = 64, Cc = 256, Tt = 64, Vv = 25;
constexpr int TV = Tt * Vv;          // 1600
constexpr int CTV = Cc * TV;         // 409600
// total elems = 26,214,400

typedef short short8 __attribute__((ext_vector_type(8)));
typedef float floatx4 __attribute__((ext_vector_type(4)));

__device__ __forceinline__ unsigned short f2bf(float f) {
    unsigned int u = __builtin_bit_cast(unsigned int, f);
    u += 0x7FFFu + ((u >> 16) & 1u);      // round-to-nearest-even
    return (unsigned short)(u >> 16);
}
__device__ __forceinline__ float bf2f(unsigned short h) {
    unsigned int u = ((unsigned int)h) << 16;
    return __builtin_bit_cast(float, u);
}

// ---------------- K0: conv_w fp32 -> bf16 (65536 elems) ----------------
__global__ __launch_bounds__(256) void k_wconv(const float* __restrict__ w,
                                               unsigned short* __restrict__ wb) {
    int i = blockIdx.x * 256 + threadIdx.x;
    wb[i] = f2bf(w[i]);
}

// ---------------- K1: BN1 per-channel stats -> s1,t1 ----------------
__global__ __launch_bounds__(512) void k_bn1_stats(const float* __restrict__ x,
                                                   const float* __restrict__ g,
                                                   const float* __restrict__ b,
                                                   float* __restrict__ s1,
                                                   float* __restrict__ t1) {
    int c = blockIdx.x;
    int tid = threadIdx.x;
    const float* xp = x + (size_t)c * TV;
    double s = 0.0, ss = 0.0;
    for (int i = tid; i < Nn * TV; i += 512) {
        int n = i / TV, e = i - n * TV;
        float v = xp[(size_t)n * CTV + e];
        s += v; ss += (double)v * v;
    }
    __shared__ double sh_s[512], sh_q[512];
    sh_s[tid] = s; sh_q[tid] = ss;
    __syncthreads();
    for (int k = 256; k > 0; k >>= 1) {
        if (tid < k) { sh_s[tid] += sh_s[tid + k]; sh_q[tid] += sh_q[tid + k]; }
        __syncthreads();
    }
    if (tid == 0) {
        double M = (double)(Nn * TV);
        double mean = sh_s[0] / M;
        double var = sh_q[0] / M - mean * mean;
        float sc = g[c] * (1.0f / sqrtf((float)var + EPSV));
        s1[c] = sc;
        t1[c] = b[c] - (float)mean * sc;
    }
}

// ------- K2: h = shift_in(BN1(x)); write transposed h_t[n][tv][c] bf16 -------
// Block: one n, one 64-wide tv tile. LDS fp32 transpose, stride 65 -> conflict-free.
__global__ __launch_bounds__(256) void k_bn1_shift(const float* __restrict__ x,
                                                   const float* __restrict__ theta,
                                                   const float* __restrict__ s1,
                                                   const float* __restrict__ t1,
                                                   unsigned short* __restrict__ ht) {
    int n = blockIdx.y;
    int tv0 = blockIdx.x * 64;
    int tid = threadIdx.x;
    int j = tid & 63;          // tv within tile
    int cl = tid >> 6;         // 0..3
    int e = tv0 + j;
    int t = e / 25;
    int v = e - t * 25;
    __shared__ float tile[128][65];
    const float* xn = x + (size_t)n * CTV;
    unsigned short* outp = ht + (size_t)n * CTV;
    for (int ch = 0; ch < 2; ++ch) {
        for (int c0 = 0; c0 < 128; c0 += 4) {
            int c = ch * 128 + c0 + cl;
            float th = theta[c];
            float pos = (float)t + th;
            float fi0 = floorf(pos);
            int i0 = (int)fi0;
            float f = pos - fi0;
            float sc = s1[c], tc = t1[c];
            const float* xc = xn + (size_t)c * TV;
            float a0 = 0.f, a1 = 0.f;
            if (i0 >= 0 && i0 < Tt) a0 = xc[i0 * 25 + v] * sc + tc;
            int i1 = i0 + 1;
            if (i1 >= 0 && i1 < Tt) a1 = xc[i1 * 25 + v] * sc + tc;
            tile[c0 + cl][j] = (1.f - f) * a0 + f * a1;
        }
        __syncthreads();
        // transpose out: lanes along c -> coalesced bf16 writes, 2-way LDS (free)
        for (int jj = tid >> 7; jj < 64; jj += 2) {
            int ccl = tid & 127;
            outp[(size_t)(tv0 + jj) * 256 + ch * 128 + ccl] = f2bf(tile[ccl][jj]);
        }
        __syncthreads();
    }
}

// ------- K3: y[n][o][tv] = relu(W h + b), bf16 MFMA 16x16x32, 64x64 tile -------
__global__ __launch_bounds__(256) void k_gemm(const unsigned short* __restrict__ ht,
                                              const unsigned short* __restrict__ wb,
                                              const float* __restrict__ bias,
                                              unsigned short* __restrict__ y) {
    int n = blockIdx.z;
    int o0 = blockIdx.y * 64;
    int tv0 = blockIdx.x * 64;
    int tid = threadIdx.x;
    int wave = tid >> 6, lane = tid & 63;
    int quad = lane >> 4, l16 = lane & 15;
    __shared__ __attribute__((aligned(16))) unsigned short A[64][40]; // pad 32->40: 2-way only
    __shared__ __attribute__((aligned(16))) unsigned short B[64][40];
    floatx4 acc[4] = {};
    const unsigned short* hb = ht + (size_t)n * CTV;
    int lrow = tid >> 2;
    int lk = (tid & 3) * 8;
    for (int k0 = 0; k0 < 256; k0 += 32) {
        const uint4 av = *(const uint4*)(wb + (size_t)(o0 + lrow) * 256 + k0 + lk);
        const uint4 bv = *(const uint4*)(hb + (size_t)(tv0 + lrow) * 256 + k0 + lk);
        __syncthreads();                      // previous compute done reading LDS
        *(uint4*)&A[lrow][lk] = av;
        *(uint4*)&B[lrow][lk] = bv;
        __syncthreads();
        short8 af = *(const short8*)&A[wave * 16 + l16][quad * 8];
#pragma unroll
        for (int jt = 0; jt < 4; ++jt) {
            short8 bf = *(const short8*)&B[jt * 16 + l16][quad * 8];
            acc[jt] = __builtin_amdgcn_mfma_f32_16x16x32_bf16(af, bf, acc[jt], 0, 0, 0);
        }
    }
    unsigned short* yb = y + (size_t)n * CTV;
#pragma unroll
    for (int jt = 0; jt < 4; ++jt) {
#pragma unroll
        for (int r = 0; r < 4; ++r) {
            int o = o0 + wave * 16 + quad * 4 + r;      // C/D: row = quad*4 + r
            int tv = tv0 + jt * 16 + l16;               //      col = lane&15
            float vv = acc[jt][r] + bias[o];
            vv = vv > 0.f ? vv : 0.f;
            yb[(size_t)o * TV + tv] = f2bf(vv);
        }
    }
}

// ------- K4: BN2 stats over z = shift_out(y) -> s2,t2 -------
__global__ __launch_bounds__(512) void k_bn2_stats(const unsigned short* __restrict__ y,
                                                   const float* __restrict__ theta,
                                                   const float* __restrict__ g,
                                                   const float* __restrict__ b,
                                                   float* __restrict__ s2,
                                                   float* __restrict__ t2) {
    int o = blockIdx.x;
    int tid = threadIdx.x;
    float th = theta[o];
    double s = 0.0, ss = 0.0;
    const unsigned short* yo = y + (size_t)o * TV;
    for (int i = tid; i < Nn * TV; i += 512) {
        int n = i / TV, e = i - n * TV;
        int t = e / 25, v = e - t * 25;
        float pos = (float)t + th;
        float fi0 = floorf(pos);
        int i0 = (int)fi0;
        float f = pos - fi0;
        const unsigned short* yp = yo + (size_t)n * CTV;
        float a0 = (i0 >= 0 && i0 < Tt) ? bf2f(yp[i0 * 25 + v]) : 0.f;
        int i1 = i0 + 1;
        float a1 = (i1 >= 0 && i1 < Tt) ? bf2f(yp[i1 * 25 + v]) : 0.f;
        float z = (1.f - f) * a0 + f * a1;
        s += z; ss += (double)z * z;
    }
    __shared__ double sh_s[512], sh_q[512];
    sh_s[tid] = s; sh_q[tid] = ss;
    __syncthreads();
    for (int k = 256; k > 0; k >>= 1) {
        if (tid < k) { sh_s[tid] += sh_s[tid + k]; sh_q[tid] += sh_q[tid + k]; }
        __syncthreads();
    }
    if (tid == 0) {
        double M = (double)(Nn * TV);
        double mean = sh_s[0] / M;
        double var = sh_q[0] / M - mean * mean;
        float sc = g[o] * (1.0f / sqrtf((float)var + EPSV));
        s2[o] = sc;
        t2[o] = b[o] - (float)mean * sc;
    }
}

// ------- K5: out = BN2(shift_out(y)) fp32 -------
__global__ __launch_bounds__(256) void k_bn2_apply(const unsigned short* __restrict__ y,
                                                   const float* __restrict__ theta,
                                                   const float* __restrict__ s2,
                                                   const float* __restrict__ t2,
                                                   float* __restrict__ out) {
    int o = blockIdx.x;
    int n = blockIdx.y;
    float th = theta[o], sc = s2[o], tc = t2[o];
    const unsigned short* yp = y + (size_t)n * CTV + (size_t)o * TV;
    float* op = out + (size_t)n * CTV + (size_t)o * TV;
    for (int e = threadIdx.x; e < TV; e += 256) {
        int t = e / 25, v = e - t * 25;
        float pos = (float)t + th;
        float fi0 = floorf(pos);
        int i0 = (int)fi0;
        float f = pos - fi0;
        float a0 = (i0 >= 0 && i0 < Tt) ? bf2f(yp[i0 * 25 + v]) : 0.f;
        int i1 = i0 + 1;
        float a1 = (i1 >= 0 && i1 < Tt) ? bf2f(yp[i1 * 25 + v]) : 0.f;
        op[e] = ((1.f - f) * a0 + f * a1) * sc + tc;
    }
}

extern "C" void kernel_launch(void* const* d_in, const int* in_sizes, int n_in,
                              void* d_out, int out_size, void* d_ws, size_t ws_size,
                              hipStream_t stream) {
    const float* x      = (const float*)d_in[0];
    const float* conv_w = (const float*)d_in[1];
    const float* conv_b = (const float*)d_in[2];
    const float* bn1_g  = (const float*)d_in[3];
    const float* bn1_b  = (const float*)d_in[4];
    const float* bn2_g  = (const float*)d_in[5];
    const float* bn2_b  = (const float*)d_in[6];
    const float* th_in  = (const float*)d_in[7];
    const float* th_out = (const float*)d_in[8];
    float* out = (float*)d_out;

    char* ws = (char*)d_ws;
    unsigned short* ht = (unsigned short*)ws;                   // 52,428,800 B
    unsigned short* yy = (unsigned short*)(ws + 52428800);      // 52,428,800 B
    unsigned short* wb = (unsigned short*)(ws + 104857600);     // 131,072 B
    float* s1 = (float*)(ws + 104988672);
    float* t1 = s1 + 256;
    float* s2 = t1 + 256;
    float* t2 = s2 + 256;

    hipLaunchKernelGGL(k_wconv, dim3(256), dim3(256), 0, stream, conv_w, wb);
    hipLaunchKernelGGL(k_bn1_stats, dim3(256), dim3(512), 0, stream, x, bn1_g, bn1_b, s1, t1);
    hipLaunchKernelGGL(k_bn1_shift, dim3(25, 64), dim3(256), 0, stream, x, th_in, s1, t1, ht);
    hipLaunchKernelGGL(k_gemm, dim3(25, 4, 64), dim3(256), 0, stream, ht, wb, conv_b, yy);
    hipLaunchKernelGGL(k_bn2_stats, dim3(256), dim3(512), 0, stream, yy, th_out, bn2_g, bn2_b, s2, t2);
    hipLaunchKernelGGL(k_bn2_apply, dim3(256, 64), dim3(256), 0, stream, yy, th_out, s2, t2, out);
}

// Round 2
// 425.292 us; speedup vs baseline: 1.3578x; 1.3578x over previous
//
#include <hip/hip_runtime.h>

// Shift-TCN fused pipeline, MI355X (gfx950).
// [memset acc=0] [K0] w fp32->bf16  [K1] BN1 partial stats (atomic)  [K2] BN1-affine + shift_in -> h_t (bf16, K-contig)
// [K3] MFMA bf16 GEMM + bias + relu -> y (bf16)  [K4] shift_out + BN2 partial stats (atomic)
// [K5] shift_out + BN2 affine -> out (fp32)

#define EPSV 1e-5f
constexpr int Nn = 64, Cc = 256, Tt = 64, Vv = 25;
constexpr int TV = Tt * Vv;          // 1600
constexpr int CTV = Cc * TV;         // 409600
constexpr float Minv = 1.0f / (Nn * TV);   // 1/102400

typedef short short8 __attribute__((ext_vector_type(8)));
typedef float floatx4 __attribute__((ext_vector_type(4)));

__device__ __forceinline__ unsigned short f2bf(float f) {
    unsigned int u = __builtin_bit_cast(unsigned int, f);
    u += 0x7FFFu + ((u >> 16) & 1u);      // round-to-nearest-even
    return (unsigned short)(u >> 16);
}
__device__ __forceinline__ float bf2f(unsigned short h) {
    unsigned int u = ((unsigned int)h) << 16;
    return __builtin_bit_cast(float, u);
}

// ---------------- K0: conv_w fp32 -> bf16 (65536 elems) ----------------
__global__ __launch_bounds__(256) void k_wconv(const float* __restrict__ w,
                                               unsigned short* __restrict__ wb) {
    int i = blockIdx.x * 256 + threadIdx.x;
    wb[i] = f2bf(w[i]);
}

// ------- K1: BN1 partial stats. grid (8 ngrp, 256 c), float4 loads, atomics -------
__global__ __launch_bounds__(256) void k_bn1_stats(const float* __restrict__ x,
                                                   float* __restrict__ sacc,
                                                   float* __restrict__ qacc) {
    int c = blockIdx.y, ng = blockIdx.x, tid = threadIdx.x;
    const float* xp = x + (size_t)(ng * 8) * CTV + (size_t)c * TV;
    float s = 0.f, q = 0.f;
    for (int n = 0; n < 8; ++n) {
        const float4* p = (const float4*)(xp + (size_t)n * CTV);
        for (int i = tid; i < 400; i += 256) {
            float4 v = p[i];
            s += (v.x + v.y) + (v.z + v.w);
            q += (v.x * v.x + v.y * v.y) + (v.z * v.z + v.w * v.w);
        }
    }
    for (int off = 32; off; off >>= 1) { s += __shfl_down(s, off); q += __shfl_down(q, off); }
    if ((tid & 63) == 0) { atomicAdd(&sacc[c], s); atomicAdd(&qacc[c], q); }
}

// ------- K2: h = shift_in(BN1(x)); write transposed h_t[n][tv][c] bf16 -------
__global__ __launch_bounds__(256) void k_bn1_shift(const float* __restrict__ x,
                                                   const float* __restrict__ theta,
                                                   const float* __restrict__ sacc,
                                                   const float* __restrict__ qacc,
                                                   const float* __restrict__ g,
                                                   const float* __restrict__ b,
                                                   unsigned short* __restrict__ ht) {
    int n = blockIdx.y;
    int tv0 = blockIdx.x * 64;
    int tid = threadIdx.x;
    int j = tid & 63;          // tv within tile
    int cl = tid >> 6;         // 0..3
    int e = tv0 + j;
    int t = e / 25;
    int v = e - t * 25;
    __shared__ float tile[128][65];
    const float* xn = x + (size_t)n * CTV;
    unsigned short* outp = ht + (size_t)n * CTV;
    for (int ch = 0; ch < 2; ++ch) {
        for (int c0 = 0; c0 < 128; c0 += 4) {
            int c = ch * 128 + c0 + cl;
            float th = theta[c];
            float fd = floorf(th);
            int d = (int)fd;
            float f = th - fd;
            float mean = sacc[c] * Minv;
            float var = qacc[c] * Minv - mean * mean;
            float sc = g[c] * rsqrtf(var + EPSV);
            float tc = b[c] - mean * sc;
            const float* xc = xn + (size_t)c * TV;
            int i0 = t + d, i1 = i0 + 1;
            float a0 = 0.f, a1 = 0.f;
            if ((unsigned)i0 < 64u) a0 = xc[i0 * 25 + v] * sc + tc;
            if ((unsigned)i1 < 64u) a1 = xc[i1 * 25 + v] * sc + tc;
            tile[c0 + cl][j] = (1.f - f) * a0 + f * a1;
        }
        __syncthreads();
        for (int jj = tid >> 7; jj < 64; jj += 2) {
            int ccl = tid & 127;
            outp[(size_t)(tv0 + jj) * 256 + ch * 128 + ccl] = f2bf(tile[ccl][jj]);
        }
        __syncthreads();
    }
}

// ------- K3: y[n][o][tv] = relu(W h + b), bf16 MFMA 16x16x32, 64x64 tile -------
__global__ __launch_bounds__(256) void k_gemm(const unsigned short* __restrict__ ht,
                                              const unsigned short* __restrict__ wb,
                                              const float* __restrict__ bias,
                                              unsigned short* __restrict__ y) {
    int n = blockIdx.z;
    int o0 = blockIdx.y * 64;
    int tv0 = blockIdx.x * 64;
    int tid = threadIdx.x;
    int wave = tid >> 6, lane = tid & 63;
    int quad = lane >> 4, l16 = lane & 15;
    __shared__ __attribute__((aligned(16))) unsigned short A[64][40];
    __shared__ __attribute__((aligned(16))) unsigned short B[64][40];
    floatx4 acc[4] = {};
    const unsigned short* hb = ht + (size_t)n * CTV;
    int lrow = tid >> 2;
    int lk = (tid & 3) * 8;
    for (int k0 = 0; k0 < 256; k0 += 32) {
        const uint4 av = *(const uint4*)(wb + (size_t)(o0 + lrow) * 256 + k0 + lk);
        const uint4 bv = *(const uint4*)(hb + (size_t)(tv0 + lrow) * 256 + k0 + lk);
        __syncthreads();
        *(uint4*)&A[lrow][lk] = av;
        *(uint4*)&B[lrow][lk] = bv;
        __syncthreads();
        short8 af = *(const short8*)&A[wave * 16 + l16][quad * 8];
#pragma unroll
        for (int jt = 0; jt < 4; ++jt) {
            short8 bf = *(const short8*)&B[jt * 16 + l16][quad * 8];
            acc[jt] = __builtin_amdgcn_mfma_f32_16x16x32_bf16(af, bf, acc[jt], 0, 0, 0);
        }
    }
    unsigned short* yb = y + (size_t)n * CTV;
#pragma unroll
    for (int jt = 0; jt < 4; ++jt) {
#pragma unroll
        for (int r = 0; r < 4; ++r) {
            int o = o0 + wave * 16 + quad * 4 + r;
            int tv = tv0 + jt * 16 + l16;
            float vv = acc[jt][r] + bias[o];
            vv = vv > 0.f ? vv : 0.f;
            yb[(size_t)o * TV + tv] = f2bf(vv);
        }
    }
}

// ------- K4: BN2 partial stats over z = shift_out(y). grid (8 ngrp, 256 o) -------
__global__ __launch_bounds__(256) void k_bn2_stats(const unsigned short* __restrict__ y,
                                                   const float* __restrict__ theta,
                                                   float* __restrict__ sacc,
                                                   float* __restrict__ qacc) {
    int o = blockIdx.y, ng = blockIdx.x, tid = threadIdx.x;
    __shared__ __attribute__((aligned(16))) unsigned short row[1600];
    float th = theta[o];
    float fd = floorf(th);
    int d = (int)fd;
    float f = th - fd;
    float s = 0.f, q = 0.f;
    for (int n = ng * 8; n < ng * 8 + 8; ++n) {
        const uint4* yp = (const uint4*)(y + (size_t)n * CTV + (size_t)o * TV);
        __syncthreads();                         // guard row overwrite
        if (tid < 200) ((uint4*)row)[tid] = yp[tid];
        __syncthreads();
        for (int e = tid; e < 1600; e += 256) {
            int t = e / 25, v = e - t * 25;
            int i0 = t + d, i1 = i0 + 1;
            float a0 = ((unsigned)i0 < 64u) ? bf2f(row[i0 * 25 + v]) : 0.f;
            float a1 = ((unsigned)i1 < 64u) ? bf2f(row[i1 * 25 + v]) : 0.f;
            float z = (1.f - f) * a0 + f * a1;
            s += z; q += z * z;
        }
    }
    for (int off = 32; off; off >>= 1) { s += __shfl_down(s, off); q += __shfl_down(q, off); }
    if ((tid & 63) == 0) { atomicAdd(&sacc[o], s); atomicAdd(&qacc[o], q); }
}

// ------- K5: out = BN2(shift_out(y)) fp32. grid (64 n, 256 o) -------
__global__ __launch_bounds__(256) void k_bn2_apply(const unsigned short* __restrict__ y,
                                                   const float* __restrict__ theta,
                                                   const float* __restrict__ sacc,
                                                   const float* __restrict__ qacc,
                                                   const float* __restrict__ g,
                                                   const float* __restrict__ b,
                                                   float* __restrict__ out) {
    int o = blockIdx.y, n = blockIdx.x, tid = threadIdx.x;
    __shared__ __attribute__((aligned(16))) unsigned short row[1600];
    float th = theta[o];
    float fd = floorf(th);
    int d = (int)fd;
    float f = th - fd;
    float mean = sacc[o] * Minv;
    float var = qacc[o] * Minv - mean * mean;
    float sc = g[o] * rsqrtf(var + EPSV);
    float tc = b[o] - mean * sc;
    const uint4* yp = (const uint4*)(y + (size_t)n * CTV + (size_t)o * TV);
    if (tid < 200) ((uint4*)row)[tid] = yp[tid];
    __syncthreads();
    float4* op = (float4*)(out + (size_t)n * CTV + (size_t)o * TV);
    for (int i = tid; i < 400; i += 256) {
        float4 r;
        int e = i * 4;
#pragma unroll
        for (int k = 0; k < 4; ++k) {
            int ee = e + k;
            int t = ee / 25, v = ee - t * 25;
            int i0 = t + d, i1 = i0 + 1;
            float a0 = ((unsigned)i0 < 64u) ? bf2f(row[i0 * 25 + v]) : 0.f;
            float a1 = ((unsigned)i1 < 64u) ? bf2f(row[i1 * 25 + v]) : 0.f;
            ((float*)&r)[k] = ((1.f - f) * a0 + f * a1) * sc + tc;
        }
        op[i] = r;
    }
}

extern "C" void kernel_launch(void* const* d_in, const int* in_sizes, int n_in,
                              void* d_out, int out_size, void* d_ws, size_t ws_size,
                              hipStream_t stream) {
    const float* x      = (const float*)d_in[0];
    const float* conv_w = (const float*)d_in[1];
    const float* conv_b = (const float*)d_in[2];
    const float* bn1_g  = (const float*)d_in[3];
    const float* bn1_b  = (const float*)d_in[4];
    const float* bn2_g  = (const float*)d_in[5];
    const float* bn2_b  = (const float*)d_in[6];
    const float* th_in  = (const float*)d_in[7];
    const float* th_out = (const float*)d_in[8];
    float* out = (float*)d_out;

    char* ws = (char*)d_ws;
    unsigned short* ht = (unsigned short*)ws;                   // 52,428,800 B
    unsigned short* yy = (unsigned short*)(ws + 52428800);      // 52,428,800 B
    unsigned short* wb = (unsigned short*)(ws + 104857600);     // 131,072 B
    float* sacc1 = (float*)(ws + 104988672);
    float* qacc1 = sacc1 + 256;
    float* sacc2 = qacc1 + 256;
    float* qacc2 = sacc2 + 256;

    hipMemsetAsync((void*)sacc1, 0, 4 * 256 * sizeof(float), stream);
    hipLaunchKernelGGL(k_wconv, dim3(256), dim3(256), 0, stream, conv_w, wb);
    hipLaunchKernelGGL(k_bn1_stats, dim3(8, 256), dim3(256), 0, stream, x, sacc1, qacc1);
    hipLaunchKernelGGL(k_bn1_shift, dim3(25, 64), dim3(256), 0, stream,
                       x, th_in, sacc1, qacc1, bn1_g, bn1_b, ht);
    hipLaunchKernelGGL(k_gemm, dim3(25, 4, 64), dim3(256), 0, stream, ht, wb, conv_b, yy);
    hipLaunchKernelGGL(k_bn2_stats, dim3(8, 256), dim3(256), 0, stream, yy, th_out, sacc2, qacc2);
    hipLaunchKernelGGL(k_bn2_apply, dim3(64, 256), dim3(256), 0, stream,
                       yy, th_out, sacc2, qacc2, bn2_g, bn2_b, out);
}

// Round 3
// 345.316 us; speedup vs baseline: 1.6722x; 1.2316x over previous
//
#include <hip/hip_runtime.h>

// Shift-TCN fused pipeline, MI355X (gfx950).
// [memset acc=0] [K0] w fp32->bf16  [K1] BN1 partial stats (atomic)  [Kp] BN1 params + shift coeffs
// [K2] BN1-affine + shift_in -> h_t (bf16, K-contig) via LDS-staged window transpose
// [K3] MFMA bf16 GEMM + bias + relu -> y (bf16)  [K4] shift_out + BN2 partial stats (atomic)
// [K5] shift_out + BN2 affine -> out (fp32)

#define EPSV 1e-5f
constexpr int Nn = 64, Cc = 256, Tt = 64, Vv = 25;
constexpr int TV = Tt * Vv;          // 1600
constexpr int CTV = Cc * TV;         // 409600
constexpr float Minv = 1.0f / (Nn * TV);   // 1/102400

typedef short short8 __attribute__((ext_vector_type(8)));
typedef float floatx4 __attribute__((ext_vector_type(4)));

__device__ __forceinline__ unsigned short f2bf(float f) {
    unsigned int u = __builtin_bit_cast(unsigned int, f);
    u += 0x7FFFu + ((u >> 16) & 1u);      // round-to-nearest-even
    return (unsigned short)(u >> 16);
}
__device__ __forceinline__ float bf2f(unsigned short h) {
    unsigned int u = ((unsigned int)h) << 16;
    return __builtin_bit_cast(float, u);
}

// ---------------- K0: conv_w fp32 -> bf16 (65536 elems) ----------------
__global__ __launch_bounds__(256) void k_wconv(const float* __restrict__ w,
                                               unsigned short* __restrict__ wb) {
    int i = blockIdx.x * 256 + threadIdx.x;
    wb[i] = f2bf(w[i]);
}

// ------- K1: BN1 partial stats. grid (8 ngrp, 256 c), float4 loads, atomics -------
__global__ __launch_bounds__(256) void k_bn1_stats(const float* __restrict__ x,
                                                   float* __restrict__ sacc,
                                                   float* __restrict__ qacc) {
    int c = blockIdx.y, ng = blockIdx.x, tid = threadIdx.x;
    const float* xp = x + (size_t)(ng * 8) * CTV + (size_t)c * TV;
    float s = 0.f, q = 0.f;
    for (int n = 0; n < 8; ++n) {
        const float4* p = (const float4*)(xp + (size_t)n * CTV);
        for (int i = tid; i < 400; i += 256) {
            float4 v = p[i];
            s += (v.x + v.y) + (v.z + v.w);
            q += (v.x * v.x + v.y * v.y) + (v.z * v.z + v.w * v.w);
        }
    }
    for (int off = 32; off; off >>= 1) { s += __shfl_down(s, off); q += __shfl_down(q, off); }
    if ((tid & 63) == 0) { atomicAdd(&sacc[c], s); atomicAdd(&qacc[c], q); }
}

// ------- Kp: finalize BN1 params + shift coeffs (1 block, 256 thr) -------
__global__ __launch_bounds__(256) void k_bnparams(const float* __restrict__ sacc,
                                                  const float* __restrict__ qacc,
                                                  const float* __restrict__ g,
                                                  const float* __restrict__ b,
                                                  const float* __restrict__ theta,
                                                  float* __restrict__ s1,
                                                  float* __restrict__ t1,
                                                  int* __restrict__ pd,
                                                  float* __restrict__ pf) {
    int c = threadIdx.x;
    float mean = sacc[c] * Minv;
    float var = qacc[c] * Minv - mean * mean;
    float sc = g[c] * rsqrtf(var + EPSV);
    s1[c] = sc;
    t1[c] = b[c] - mean * sc;
    float th = theta[c];
    float fd = floorf(th);
    pd[c] = (int)fd;
    pf[c] = th - fd;
}

// ------- K2: h = shift_in(BN1(x)) -> ht[n][tv][c] bf16 (K-contig) -------
// grid (16 c-grp, 4 t-tile, 64 n). Stage 16c x 456-float x-window (t-halo +-25)
// via aligned float4; blend+affine+transpose out as uint4 (8 bf16 along c).
__global__ __launch_bounds__(256) void k_bn1_shift(const float* __restrict__ x,
                                                   const float* __restrict__ s1,
                                                   const float* __restrict__ t1,
                                                   const int* __restrict__ pd,
                                                   const float* __restrict__ pf,
                                                   unsigned short* __restrict__ ht) {
    int c0 = blockIdx.x * 16;
    int tile = blockIdx.y;
    int n = blockIdx.z;
    int tid = threadIdx.x;
    __shared__ __attribute__((aligned(16))) float lds[16][460]; // 460*4 % 16 == 0
    __shared__ float psc[16], ptc[16], pfr[16];
    __shared__ int pdd[16], pww[16];

    if (tid < 16) {
        int c = c0 + tid;
        int d = pd[c];
        pdd[tid] = d;
        pww[tid] = 28 + d * 25;
        pfr[tid] = pf[c];
        psc[tid] = s1[c];
        ptc[tid] = t1[c];
    }

    int E0 = tile * 400;                 // tile covers e in [E0, E0+400)
    int lo = E0 - 28; if (lo < 0) lo = 0;
    int hi = E0 + 428; if (hi > 1600) hi = 1600;
    int ldsoff = lo - (E0 - 28);         // 0 or 28 (multiple of 4)
    int nf4 = (hi - lo) >> 2;
    {
        int ci = tid >> 4, li = tid & 15;
        const float4* xrow = (const float4*)(x + (size_t)n * CTV + (size_t)(c0 + ci) * TV + lo);
        float* lrow = &lds[ci][ldsoff];
        for (int i = li; i < nf4; i += 16)
            *(float4*)(lrow + i * 4) = xrow[i];
    }
    __syncthreads();

    int oct = tid & 1, tvr = tid >> 1;
    unsigned short* outb = ht + (size_t)n * CTV + c0 + oct * 8;
    for (int tv_l = tvr; tv_l < 400; tv_l += 128) {
        int e = E0 + tv_l;
        int t = e / 25;
        unsigned int wrds[4];
#pragma unroll
        for (int k = 0; k < 8; ++k) {
            int ci = oct * 8 + k;
            int i0 = t + pdd[ci];
            int w0 = tv_l + pww[ci];
            float x0 = lds[ci][w0];
            float x1 = lds[ci][w0 + 25];
            float sc = psc[ci], tc = ptc[ci], f = pfr[ci];
            float b0 = ((unsigned)i0 < 64u) ? (x0 * sc + tc) : 0.f;
            float b1 = ((unsigned)(i0 + 1) < 64u) ? (x1 * sc + tc) : 0.f;
            unsigned short hb = f2bf(b0 + f * (b1 - b0));
            if (k & 1) wrds[k >> 1] |= ((unsigned int)hb) << 16;
            else       wrds[k >> 1] = hb;
        }
        uint4 st = { wrds[0], wrds[1], wrds[2], wrds[3] };
        *(uint4*)(outb + (size_t)e * 256) = st;
    }
}

// ------- K3: y[n][o][tv] = relu(W h + b), bf16 MFMA 16x16x32, 64x64 tile -------
__global__ __launch_bounds__(256) void k_gemm(const unsigned short* __restrict__ ht,
                                              const unsigned short* __restrict__ wb,
                                              const float* __restrict__ bias,
                                              unsigned short* __restrict__ y) {
    int n = blockIdx.z;
    int o0 = blockIdx.y * 64;
    int tv0 = blockIdx.x * 64;
    int tid = threadIdx.x;
    int wave = tid >> 6, lane = tid & 63;
    int quad = lane >> 4, l16 = lane & 15;
    __shared__ __attribute__((aligned(16))) unsigned short A[64][40];
    __shared__ __attribute__((aligned(16))) unsigned short B[64][40];
    floatx4 acc[4] = {};
    const unsigned short* hb = ht + (size_t)n * CTV;
    int lrow = tid >> 2;
    int lk = (tid & 3) * 8;
    for (int k0 = 0; k0 < 256; k0 += 32) {
        const uint4 av = *(const uint4*)(wb + (size_t)(o0 + lrow) * 256 + k0 + lk);
        const uint4 bv = *(const uint4*)(hb + (size_t)(tv0 + lrow) * 256 + k0 + lk);
        __syncthreads();
        *(uint4*)&A[lrow][lk] = av;
        *(uint4*)&B[lrow][lk] = bv;
        __syncthreads();
        short8 af = *(const short8*)&A[wave * 16 + l16][quad * 8];
#pragma unroll
        for (int jt = 0; jt < 4; ++jt) {
            short8 bf = *(const short8*)&B[jt * 16 + l16][quad * 8];
            acc[jt] = __builtin_amdgcn_mfma_f32_16x16x32_bf16(af, bf, acc[jt], 0, 0, 0);
        }
    }
    unsigned short* yb = y + (size_t)n * CTV;
#pragma unroll
    for (int jt = 0; jt < 4; ++jt) {
#pragma unroll
        for (int r = 0; r < 4; ++r) {
            int o = o0 + wave * 16 + quad * 4 + r;
            int tv = tv0 + jt * 16 + l16;
            float vv = acc[jt][r] + bias[o];
            vv = vv > 0.f ? vv : 0.f;
            yb[(size_t)o * TV + tv] = f2bf(vv);
        }
    }
}

// ------- K4: BN2 partial stats over z = shift_out(y). grid (8 ngrp, 256 o) -------
__global__ __launch_bounds__(256) void k_bn2_stats(const unsigned short* __restrict__ y,
                                                   const float* __restrict__ theta,
                                                   float* __restrict__ sacc,
                                                   float* __restrict__ qacc) {
    int o = blockIdx.y, ng = blockIdx.x, tid = threadIdx.x;
    __shared__ __attribute__((aligned(16))) unsigned short row[1600];
    float th = theta[o];
    float fd = floorf(th);
    int d = (int)fd;
    float f = th - fd;
    float s = 0.f, q = 0.f;
    for (int n = ng * 8; n < ng * 8 + 8; ++n) {
        const uint4* yp = (const uint4*)(y + (size_t)n * CTV + (size_t)o * TV);
        __syncthreads();                         // guard row overwrite
        if (tid < 200) ((uint4*)row)[tid] = yp[tid];
        __syncthreads();
        for (int e = tid; e < 1600; e += 256) {
            int t = e / 25, v = e - t * 25;
            int i0 = t + d, i1 = i0 + 1;
            float a0 = ((unsigned)i0 < 64u) ? bf2f(row[i0 * 25 + v]) : 0.f;
            float a1 = ((unsigned)i1 < 64u) ? bf2f(row[i1 * 25 + v]) : 0.f;
            float z = (1.f - f) * a0 + f * a1;
            s += z; q += z * z;
        }
    }
    for (int off = 32; off; off >>= 1) { s += __shfl_down(s, off); q += __shfl_down(q, off); }
    if ((tid & 63) == 0) { atomicAdd(&sacc[o], s); atomicAdd(&qacc[o], q); }
}

// ------- K5: out = BN2(shift_out(y)) fp32. grid (64 n, 256 o) -------
__global__ __launch_bounds__(256) void k_bn2_apply(const unsigned short* __restrict__ y,
                                                   const float* __restrict__ theta,
                                                   const float* __restrict__ sacc,
                                                   const float* __restrict__ qacc,
                                                   const float* __restrict__ g,
                                                   const float* __restrict__ b,
                                                   float* __restrict__ out) {
    int o = blockIdx.y, n = blockIdx.x, tid = threadIdx.x;
    __shared__ __attribute__((aligned(16))) unsigned short row[1600];
    float th = theta[o];
    float fd = floorf(th);
    int d = (int)fd;
    float f = th - fd;
    float mean = sacc[o] * Minv;
    float var = qacc[o] * Minv - mean * mean;
    float sc = g[o] * rsqrtf(var + EPSV);
    float tc = b[o] - mean * sc;
    const uint4* yp = (const uint4*)(y + (size_t)n * CTV + (size_t)o * TV);
    if (tid < 200) ((uint4*)row)[tid] = yp[tid];
    __syncthreads();
    float4* op = (float4*)(out + (size_t)n * CTV + (size_t)o * TV);
    for (int i = tid; i < 400; i += 256) {
        float4 r;
        int e = i * 4;
#pragma unroll
        for (int k = 0; k < 4; ++k) {
            int ee = e + k;
            int t = ee / 25, v = ee - t * 25;
            int i0 = t + d, i1 = i0 + 1;
            float a0 = ((unsigned)i0 < 64u) ? bf2f(row[i0 * 25 + v]) : 0.f;
            float a1 = ((unsigned)i1 < 64u) ? bf2f(row[i1 * 25 + v]) : 0.f;
            ((float*)&r)[k] = ((1.f - f) * a0 + f * a1) * sc + tc;
        }
        op[i] = r;
    }
}

extern "C" void kernel_launch(void* const* d_in, const int* in_sizes, int n_in,
                              void* d_out, int out_size, void* d_ws, size_t ws_size,
                              hipStream_t stream) {
    const float* x      = (const float*)d_in[0];
    const float* conv_w = (const float*)d_in[1];
    const float* conv_b = (const float*)d_in[2];
    const float* bn1_g  = (const float*)d_in[3];
    const float* bn1_b  = (const float*)d_in[4];
    const float* bn2_g  = (const float*)d_in[5];
    const float* bn2_b  = (const float*)d_in[6];
    const float* th_in  = (const float*)d_in[7];
    const float* th_out = (const float*)d_in[8];
    float* out = (float*)d_out;

    char* ws = (char*)d_ws;
    unsigned short* ht = (unsigned short*)ws;                   // 52,428,800 B
    unsigned short* yy = (unsigned short*)(ws + 52428800);      // 52,428,800 B
    unsigned short* wb = (unsigned short*)(ws + 104857600);     // 131,072 B
    float* sacc1 = (float*)(ws + 104988672);
    float* qacc1 = sacc1 + 256;
    float* sacc2 = qacc1 + 256;
    float* qacc2 = sacc2 + 256;
    float* s1    = qacc2 + 256;
    float* t1    = s1 + 256;
    float* pf1   = t1 + 256;
    int*   pd1   = (int*)(pf1 + 256);

    hipMemsetAsync((void*)sacc1, 0, 4 * 256 * sizeof(float), stream);
    hipLaunchKernelGGL(k_wconv, dim3(256), dim3(256), 0, stream, conv_w, wb);
    hipLaunchKernelGGL(k_bn1_stats, dim3(8, 256), dim3(256), 0, stream, x, sacc1, qacc1);
    hipLaunchKernelGGL(k_bnparams, dim3(1), dim3(256), 0, stream,
                       sacc1, qacc1, bn1_g, bn1_b, th_in, s1, t1, pd1, pf1);
    hipLaunchKernelGGL(k_bn1_shift, dim3(16, 4, 64), dim3(256), 0, stream,
                       x, s1, t1, pd1, pf1, ht);
    hipLaunchKernelGGL(k_gemm, dim3(25, 4, 64), dim3(256), 0, stream, ht, wb, conv_b, yy);
    hipLaunchKernelGGL(k_bn2_stats, dim3(8, 256), dim3(256), 0, stream, yy, th_out, sacc2, qacc2);
    hipLaunchKernelGGL(k_bn2_apply, dim3(64, 256), dim3(256), 0, stream,
                       yy, th_out, sacc2, qacc2, bn2_g, bn2_b, out);
}

// Round 4
// 332.228 us; speedup vs baseline: 1.7381x; 1.0394x over previous
//
#include <hip/hip_runtime.h>

// Shift-TCN fused pipeline, MI355X (gfx950).
// [memset acc=0]
// [K1] BN1 partial stats (atomic) + w fp32->bf16 (fused grid slice)
// [K2] BN1 param finalize (per-block, 16ch) + affine + shift_in -> h_t (bf16, K-contig)
// [K3] MFMA bf16 GEMM 128x128 tiles, flattened J=(n,tv), global_load_lds staging, +bias+relu -> y bf16
// [K4] shift_out + BN2 partial stats (atomic)
// [K5] shift_out + BN2 affine -> out (fp32)

#define EPSV 1e-5f
constexpr int Nn = 64, Cc = 256, Tt = 64, Vv = 25;
constexpr int TV = Tt * Vv;          // 1600
constexpr int CTV = Cc * TV;         // 409600
constexpr float Minv = 1.0f / (Nn * TV);   // 1/102400

typedef short short8 __attribute__((ext_vector_type(8)));
typedef float floatx4 __attribute__((ext_vector_type(4)));

__device__ __forceinline__ unsigned short f2bf(float f) {
    unsigned int u = __builtin_bit_cast(unsigned int, f);
    u += 0x7FFFu + ((u >> 16) & 1u);      // round-to-nearest-even
    return (unsigned short)(u >> 16);
}
__device__ __forceinline__ float bf2f(unsigned short h) {
    unsigned int u = ((unsigned int)h) << 16;
    return __builtin_bit_cast(float, u);
}
__device__ __forceinline__ void gload_lds16(const void* g, void* l) {
    __builtin_amdgcn_global_load_lds((const __attribute__((address_space(1))) void*)g,
                                     (__attribute__((address_space(3))) void*)l, 16, 0, 0);
}

// ------- K1: BN1 partial stats, grid (8, 257); y==256 slice converts conv_w -------
__global__ __launch_bounds__(256) void k_bn1_stats(const float* __restrict__ x,
                                                   const float* __restrict__ w,
                                                   unsigned short* __restrict__ wb,
                                                   float* __restrict__ sacc,
                                                   float* __restrict__ qacc) {
    int c = blockIdx.y, ng = blockIdx.x, tid = threadIdx.x;
    if (c == 256) {            // fused conv_w fp32->bf16 (65536 elems over 8 blocks)
        int base = ng * 8192 + tid;
#pragma unroll
        for (int i = 0; i < 32; ++i) wb[base + i * 256] = f2bf(w[base + i * 256]);
        return;
    }
    const float* xp = x + (size_t)(ng * 8) * CTV + (size_t)c * TV;
    float s = 0.f, q = 0.f;
    for (int n = 0; n < 8; ++n) {
        const float4* p = (const float4*)(xp + (size_t)n * CTV);
        for (int i = tid; i < 400; i += 256) {
            float4 v = p[i];
            s += (v.x + v.y) + (v.z + v.w);
            q += (v.x * v.x + v.y * v.y) + (v.z * v.z + v.w * v.w);
        }
    }
    for (int off = 32; off; off >>= 1) { s += __shfl_down(s, off); q += __shfl_down(q, off); }
    if ((tid & 63) == 0) { atomicAdd(&sacc[c], s); atomicAdd(&qacc[c], q); }
}

// ------- K2: h = shift_in(BN1(x)) -> ht[n][tv][c] bf16 (K-contig) -------
// grid (16 c-grp, 4 t-tile, 64 n). BN1 params computed in-block (16ch).
__global__ __launch_bounds__(256) void k_bn1_shift(const float* __restrict__ x,
                                                   const float* __restrict__ sacc,
                                                   const float* __restrict__ qacc,
                                                   const float* __restrict__ g,
                                                   const float* __restrict__ b,
                                                   const float* __restrict__ theta,
                                                   unsigned short* __restrict__ ht) {
    int c0 = blockIdx.x * 16;
    int tile = blockIdx.y;
    int n = blockIdx.z;
    int tid = threadIdx.x;
    __shared__ __attribute__((aligned(16))) float lds[16][460];
    __shared__ float psc[16], ptc[16], pfr[16];
    __shared__ int pdd[16], pww[16];

    if (tid < 16) {
        int c = c0 + tid;
        float mean = sacc[c] * Minv;
        float var = qacc[c] * Minv - mean * mean;
        float sc = g[c] * rsqrtf(var + EPSV);
        float th = theta[c];
        float fd = floorf(th);
        int d = (int)fd;
        pdd[tid] = d;
        pww[tid] = 28 + d * 25;
        pfr[tid] = th - fd;
        psc[tid] = sc;
        ptc[tid] = b[c] - mean * sc;
    }

    int E0 = tile * 400;
    int lo = E0 - 28; if (lo < 0) lo = 0;
    int hi = E0 + 428; if (hi > 1600) hi = 1600;
    int ldsoff = lo - (E0 - 28);         // 0 or 28 (multiple of 4)
    int nf4 = (hi - lo) >> 2;
    {
        int ci = tid >> 4, li = tid & 15;
        const float4* xrow = (const float4*)(x + (size_t)n * CTV + (size_t)(c0 + ci) * TV + lo);
        float* lrow = &lds[ci][ldsoff];
        for (int i = li; i < nf4; i += 16)
            *(float4*)(lrow + i * 4) = xrow[i];
    }
    __syncthreads();

    int oct = tid & 1, tvr = tid >> 1;
    unsigned short* outb = ht + (size_t)n * CTV + c0 + oct * 8;
    for (int tv_l = tvr; tv_l < 400; tv_l += 128) {
        int e = E0 + tv_l;
        int t = e / 25;
        unsigned int wrds[4];
#pragma unroll
        for (int k = 0; k < 8; ++k) {
            int ci = oct * 8 + k;
            int i0 = t + pdd[ci];
            int w0 = tv_l + pww[ci];
            float x0 = lds[ci][w0];
            float x1 = lds[ci][w0 + 25];
            float sc = psc[ci], tc = ptc[ci], f = pfr[ci];
            float b0 = ((unsigned)i0 < 64u) ? (x0 * sc + tc) : 0.f;
            float b1 = ((unsigned)(i0 + 1) < 64u) ? (x1 * sc + tc) : 0.f;
            unsigned short hb = f2bf(b0 + f * (b1 - b0));
            if (k & 1) wrds[k >> 1] |= ((unsigned int)hb) << 16;
            else       wrds[k >> 1] = hb;
        }
        uint4 st = { wrds[0], wrds[1], wrds[2], wrds[3] };
        *(uint4*)(outb + (size_t)e * 256) = st;
    }
}

// ------- K3: y = relu(W h + b). Flattened J GEMM, 128x128 tile, grid (800, 2) -------
// ht rows j = n*1600+tv are K-contiguous; 64-wide j-halves never cross n (1600%64==0).
__global__ __launch_bounds__(256) void k_gemm(const unsigned short* __restrict__ ht,
                                              const unsigned short* __restrict__ wb,
                                              const float* __restrict__ bias,
                                              unsigned short* __restrict__ y) {
    int j0 = blockIdx.x * 128;
    int o0 = blockIdx.y * 128;
    int tid = threadIdx.x;
    int w = tid >> 6, lane = tid & 63;
    int quad = lane >> 4, l16 = lane & 15;
    __shared__ __attribute__((aligned(16))) unsigned short A[128 * 32];
    __shared__ __attribute__((aligned(16))) unsigned short B[128 * 32];
    floatx4 acc[4][4] = {};
    // staging: wave w covers rows [w*32, w*32+32) of A and B; 2 insts of 16 rows each
    int srow = w * 32 + (lane >> 2);
    int skcol = (lane & 3) * 8;                       // shorts
    const unsigned short* wp0 = wb + (size_t)(o0 + srow) * 256 + skcol;
    const unsigned short* hp0 = ht + (size_t)(j0 + srow) * 256 + skcol;
    int oh = w >> 1, jh = w & 1;
    for (int k0 = 0; k0 < 256; k0 += 32) {
        __syncthreads();                              // prev iter done reading LDS
#pragma unroll
        for (int a = 0; a < 2; ++a) {
            gload_lds16(wp0 + (size_t)a * 16 * 256 + k0, A + (w * 32 + a * 16) * 32);
            gload_lds16(hp0 + (size_t)a * 16 * 256 + k0, B + (w * 32 + a * 16) * 32);
        }
        __syncthreads();                              // loads complete (vmcnt drain)
        short8 af[4], bf[4];
#pragma unroll
        for (int m = 0; m < 4; ++m)
            af[m] = *(const short8*)&A[(oh * 64 + m * 16 + l16) * 32 + quad * 8];
#pragma unroll
        for (int jt = 0; jt < 4; ++jt)
            bf[jt] = *(const short8*)&B[(jh * 64 + jt * 16 + l16) * 32 + quad * 8];
#pragma unroll
        for (int m = 0; m < 4; ++m)
#pragma unroll
            for (int jt = 0; jt < 4; ++jt)
                acc[m][jt] = __builtin_amdgcn_mfma_f32_16x16x32_bf16(af[m], bf[jt], acc[m][jt], 0, 0, 0);
    }
    int jbase = j0 + jh * 64;
    int n = jbase / 1600;
    int tvb = jbase - n * 1600;
    unsigned short* yb = y + (size_t)n * CTV + tvb;
#pragma unroll
    for (int m = 0; m < 4; ++m) {
        int o = o0 + oh * 64 + m * 16 + quad * 4;
#pragma unroll
        for (int r = 0; r < 4; ++r) {
            float bia = bias[o + r];
            unsigned short* yrow = yb + (size_t)(o + r) * TV;
#pragma unroll
            for (int jt = 0; jt < 4; ++jt) {
                float vv = acc[m][jt][r] + bia;
                vv = vv > 0.f ? vv : 0.f;
                yrow[jt * 16 + l16] = f2bf(vv);
            }
        }
    }
}

// ------- K4: BN2 partial stats over z = shift_out(y). grid (8 ngrp, 256 o) -------
__global__ __launch_bounds__(256) void k_bn2_stats(const unsigned short* __restrict__ y,
                                                   const float* __restrict__ theta,
                                                   float* __restrict__ sacc,
                                                   float* __restrict__ qacc) {
    int o = blockIdx.y, ng = blockIdx.x, tid = threadIdx.x;
    __shared__ __attribute__((aligned(16))) unsigned short row[1600];
    float th = theta[o];
    float fd = floorf(th);
    int d = (int)fd;
    float f = th - fd;
    float s = 0.f, q = 0.f;
    for (int n = ng * 8; n < ng * 8 + 8; ++n) {
        const uint4* yp = (const uint4*)(y + (size_t)n * CTV + (size_t)o * TV);
        __syncthreads();
        if (tid < 200) ((uint4*)row)[tid] = yp[tid];
        __syncthreads();
        for (int e = tid; e < 1600; e += 256) {
            int t = e / 25, v = e - t * 25;
            int i0 = t + d, i1 = i0 + 1;
            float a0 = ((unsigned)i0 < 64u) ? bf2f(row[i0 * 25 + v]) : 0.f;
            float a1 = ((unsigned)i1 < 64u) ? bf2f(row[i1 * 25 + v]) : 0.f;
            float z = (1.f - f) * a0 + f * a1;
            s += z; q += z * z;
        }
    }
    for (int off = 32; off; off >>= 1) { s += __shfl_down(s, off); q += __shfl_down(q, off); }
    if ((tid & 63) == 0) { atomicAdd(&sacc[o], s); atomicAdd(&qacc[o], q); }
}

// ------- K5: out = BN2(shift_out(y)) fp32. grid (64 n, 256 o) -------
__global__ __launch_bounds__(256) void k_bn2_apply(const unsigned short* __restrict__ y,
                                                   const float* __restrict__ theta,
                                                   const float* __restrict__ sacc,
                                                   const float* __restrict__ qacc,
                                                   const float* __restrict__ g,
                                                   const float* __restrict__ b,
                                                   float* __restrict__ out) {
    int o = blockIdx.y, n = blockIdx.x, tid = threadIdx.x;
    __shared__ __attribute__((aligned(16))) unsigned short row[1600];
    float th = theta[o];
    float fd = floorf(th);
    int d = (int)fd;
    float f = th - fd;
    float mean = sacc[o] * Minv;
    float var = qacc[o] * Minv - mean * mean;
    float sc = g[o] * rsqrtf(var + EPSV);
    float tc = b[o] - mean * sc;
    const uint4* yp = (const uint4*)(y + (size_t)n * CTV + (size_t)o * TV);
    if (tid < 200) ((uint4*)row)[tid] = yp[tid];
    __syncthreads();
    float4* op = (float4*)(out + (size_t)n * CTV + (size_t)o * TV);
    for (int i = tid; i < 400; i += 256) {
        float4 r;
        int e = i * 4;
#pragma unroll
        for (int k = 0; k < 4; ++k) {
            int ee = e + k;
            int t = ee / 25, v = ee - t * 25;
            int i0 = t + d, i1 = i0 + 1;
            float a0 = ((unsigned)i0 < 64u) ? bf2f(row[i0 * 25 + v]) : 0.f;
            float a1 = ((unsigned)i1 < 64u) ? bf2f(row[i1 * 25 + v]) : 0.f;
            ((float*)&r)[k] = ((1.f - f) * a0 + f * a1) * sc + tc;
        }
        op[i] = r;
    }
}

extern "C" void kernel_launch(void* const* d_in, const int* in_sizes, int n_in,
                              void* d_out, int out_size, void* d_ws, size_t ws_size,
                              hipStream_t stream) {
    const float* x      = (const float*)d_in[0];
    const float* conv_w = (const float*)d_in[1];
    const float* conv_b = (const float*)d_in[2];
    const float* bn1_g  = (const float*)d_in[3];
    const float* bn1_b  = (const float*)d_in[4];
    const float* bn2_g  = (const float*)d_in[5];
    const float* bn2_b  = (const float*)d_in[6];
    const float* th_in  = (const float*)d_in[7];
    const float* th_out = (const float*)d_in[8];
    float* out = (float*)d_out;

    char* ws = (char*)d_ws;
    unsigned short* ht = (unsigned short*)ws;                   // 52,428,800 B
    unsigned short* yy = (unsigned short*)(ws + 52428800);      // 52,428,800 B
    unsigned short* wb = (unsigned short*)(ws + 104857600);     // 131,072 B
    float* sacc1 = (float*)(ws + 104988672);
    float* qacc1 = sacc1 + 256;
    float* sacc2 = qacc1 + 256;
    float* qacc2 = sacc2 + 256;

    hipMemsetAsync((void*)sacc1, 0, 4 * 256 * sizeof(float), stream);
    hipLaunchKernelGGL(k_bn1_stats, dim3(8, 257), dim3(256), 0, stream,
                       x, conv_w, wb, sacc1, qacc1);
    hipLaunchKernelGGL(k_bn1_shift, dim3(16, 4, 64), dim3(256), 0, stream,
                       x, sacc1, qacc1, bn1_g, bn1_b, th_in, ht);
    hipLaunchKernelGGL(k_gemm, dim3(800, 2), dim3(256), 0, stream, ht, wb, conv_b, yy);
    hipLaunchKernelGGL(k_bn2_stats, dim3(8, 256), dim3(256), 0, stream, yy, th_out, sacc2, qacc2);
    hipLaunchKernelGGL(k_bn2_apply, dim3(64, 256), dim3(256), 0, stream,
                       yy, th_out, sacc2, qacc2, bn2_g, bn2_b, out);
}